// Round 19
// baseline (569.888 us; speedup 1.0000x reference)
//
#include <hip/hip_runtime.h>
#include <math.h>

#define N_NODES 64512
#define DIN 84
#define DH 128
#define NPG 1008
#define BG 64
#define NSNAP 12
#define NSEG 84
#define NEDGE (N_NODES * 16)
#define DEGCAP 64
#define ATT_SCALE 0.08838834764831845f /* 1/sqrt(128) */

typedef __bf16 bf16_t;
typedef __bf16 bf16x8 __attribute__((ext_vector_type(8)));
typedef __bf16 bf16x4 __attribute__((ext_vector_type(4)));
typedef float f32x4 __attribute__((ext_vector_type(4)));
typedef _Float16 f16_t;
typedef _Float16 f16x4 __attribute__((ext_vector_type(4)));

__device__ __forceinline__ f32x4 up4(f16x4 v) {
    return (f32x4){(float)v[0], (float)v[1], (float)v[2], (float)v[3]};
}

// ---------------------------------------------------------------------------
// cvt_xh: x -> fp16 copy; low blocks also zero the CSR counters
// ---------------------------------------------------------------------------
__global__ __launch_bounds__(256) void cvt_xh(const float* __restrict__ x,
                                              f16_t* __restrict__ xh,
                                              int* __restrict__ cnt) {
    int t = blockIdx.x * 256 + threadIdx.x;
    int idx = t * 4;
    if (idx < N_NODES * DIN) {
        f32x4 v = *(const f32x4*)(x + idx);
        f16x4 o;
        o[0] = (f16_t)v[0]; o[1] = (f16_t)v[1];
        o[2] = (f16_t)v[2]; o[3] = (f16_t)v[3];
        *(f16x4*)(xh + idx) = o;
    }
    if (idx < N_NODES) {
        int4 z = {0, 0, 0, 0};
        *(int4*)(cnt + idx) = z;
    }
}

// ---------------------------------------------------------------------------
// Padded-CSR build: one atomic pass. deg ~ Poisson(16), P(deg>64) ~ 0.
// ---------------------------------------------------------------------------
__global__ void fill_pad(const int* __restrict__ src, const int* __restrict__ dst,
                         int* __restrict__ cnt, int* __restrict__ eidx) {
    int e = blockIdx.x * blockDim.x + threadIdx.x;
    if (e < NEDGE) {
        int d = dst[e];
        int p = atomicAdd(&cnt[d], 1);
        if (p < DEGCAP) eidx[(size_t)d * DEGCAP + p] = src[e];
    }
}

// ---------------------------------------------------------------------------
// gin1: fused gather(fp16 x) + linear1
// ---------------------------------------------------------------------------
__global__ __launch_bounds__(128) void gin1(const float* __restrict__ x,
                                            const f16_t* __restrict__ xh,
                                            const int* __restrict__ cnt,
                                            const int* __restrict__ eidx,
                                            const float* __restrict__ w1,
                                            const float* __restrict__ b1,
                                            float* __restrict__ h1,
                                            f16_t* __restrict__ h1h) {
    __shared__ float xs[8][DIN];
    int n0 = blockIdx.x * 8;
    int tid = threadIdx.x;
    int grp = tid >> 4;
    int gl = tid & 15;
    int node = n0 + grp;
    int s = node * DEGCAP;
    int e = s + min(cnt[node], DEGCAP);
    bool has2 = gl < 5;

    const float* xn = x + (size_t)node * DIN;
    f32x4 a0 = *(const f32x4*)(xn + gl * 4);
    f32x4 a1 = has2 ? *(const f32x4*)(xn + 64 + gl * 4) : (f32x4){0.f, 0.f, 0.f, 0.f};

    int i = s;
    for (; i + 4 <= e; i += 4) {
        const f16_t* p0 = xh + (size_t)eidx[i] * DIN + gl * 4;
        const f16_t* p1 = xh + (size_t)eidx[i + 1] * DIN + gl * 4;
        const f16_t* p2 = xh + (size_t)eidx[i + 2] * DIN + gl * 4;
        const f16_t* p3 = xh + (size_t)eidx[i + 3] * DIN + gl * 4;
        a0 += up4(*(const f16x4*)p0) + up4(*(const f16x4*)p1) +
              up4(*(const f16x4*)p2) + up4(*(const f16x4*)p3);
        if (has2) {
            a1 += up4(*(const f16x4*)(p0 + 64)) + up4(*(const f16x4*)(p1 + 64)) +
                  up4(*(const f16x4*)(p2 + 64)) + up4(*(const f16x4*)(p3 + 64));
        }
    }
    for (; i < e; i++) {
        const f16_t* p0 = xh + (size_t)eidx[i] * DIN + gl * 4;
        a0 += up4(*(const f16x4*)p0);
        if (has2) a1 += up4(*(const f16x4*)(p0 + 64));
    }
    *(f32x4*)&xs[grp][gl * 4] = a0;
    if (has2) *(f32x4*)&xs[grp][64 + gl * 4] = a1;
    __syncthreads();

    float acc[8];
    float bias = b1[tid];
#pragma unroll
    for (int r = 0; r < 8; r++) acc[r] = bias;
    for (int k = 0; k < DIN; k++) {
        float w = w1[k * DH + tid];
#pragma unroll
        for (int r = 0; r < 8; r++) acc[r] += xs[r][k] * w;
    }
#pragma unroll
    for (int r = 0; r < 8; r++) {
        h1[(size_t)(n0 + r) * DH + tid] = acc[r];
        h1h[(size_t)(n0 + r) * DH + tid] = (f16_t)acc[r];
    }
}

// ---------------------------------------------------------------------------
// gin2: fused gather(fp16 h1) + linear2 + pe; emits h2bf AND h2T directly.
// ---------------------------------------------------------------------------
__global__ __launch_bounds__(128) void gin2(const float* __restrict__ h1,
                                            const f16_t* __restrict__ h1h,
                                            const int* __restrict__ cnt,
                                            const int* __restrict__ eidx,
                                            const float* __restrict__ w2,
                                            const float* __restrict__ b2,
                                            const float* __restrict__ pe,
                                            bf16_t* __restrict__ h2bf,
                                            bf16_t* __restrict__ h2T) {
    __shared__ float hs[8][DH];
    int n0 = blockIdx.x * 8;
    int tid = threadIdx.x;
    int grp = tid >> 4;
    int gl = tid & 15;
    int node = n0 + grp;
    int s = node * DEGCAP;
    int e = s + min(cnt[node], DEGCAP);

    const float* hn = h1 + (size_t)node * DH;
    f32x4 a0 = *(const f32x4*)(hn + gl * 8);
    f32x4 a1 = *(const f32x4*)(hn + gl * 8 + 4);

    int i = s;
    for (; i + 4 <= e; i += 4) {
        const f16_t* p0 = h1h + (size_t)eidx[i] * DH + gl * 8;
        const f16_t* p1 = h1h + (size_t)eidx[i + 1] * DH + gl * 8;
        const f16_t* p2 = h1h + (size_t)eidx[i + 2] * DH + gl * 8;
        const f16_t* p3 = h1h + (size_t)eidx[i + 3] * DH + gl * 8;
        a0 += up4(*(const f16x4*)p0) + up4(*(const f16x4*)p1) +
              up4(*(const f16x4*)p2) + up4(*(const f16x4*)p3);
        a1 += up4(*(const f16x4*)(p0 + 4)) + up4(*(const f16x4*)(p1 + 4)) +
              up4(*(const f16x4*)(p2 + 4)) + up4(*(const f16x4*)(p3 + 4));
    }
    for (; i < e; i++) {
        const f16_t* p0 = h1h + (size_t)eidx[i] * DH + gl * 8;
        a0 += up4(*(const f16x4*)p0);
        a1 += up4(*(const f16x4*)(p0 + 4));
    }
    *(f32x4*)&hs[grp][gl * 8] = a0;
    *(f32x4*)&hs[grp][gl * 8 + 4] = a1;
    __syncthreads();

    float acc[8];
    float bias = b2[tid];
#pragma unroll
    for (int r = 0; r < 8; r++) acc[r] = bias;
    for (int k = 0; k < DH; k++) {
        float w = w2[k * DH + tid];
#pragma unroll
        for (int r = 0; r < 8; r++) acc[r] += hs[r][k] * w;
    }

    int bg = n0 / NPG;
    int pos0 = n0 - bg * NPG;
    bf16x8 tv;
#pragma unroll
    for (int r = 0; r < 8; r++) {
        bf16_t v = (bf16_t)(acc[r] + pe[(pos0 + r) * DH + tid]);
        h2bf[(size_t)(n0 + r) * DH + tid] = v;
        tv[r] = v;
    }
    *(bf16x8*)(h2T + ((size_t)bg * DH + tid) * NPG + pos0) = tv;
}

// ---------------------------------------------------------------------------
// Flash MFMA attention: wide-Q + XCD swizzle (proven R18) + split-K retry.
//   grid = 8 xcd * 2 half * 8 qt * 8 bhi = 1024 -> 4 blocks/CU.
//   LDS: smem[0..9215] = Ks (S-phase) aliased with Ps (PV-phase);
//        smem[9216..18431] = Kt. 36864 B total (R15-validated barriers).
//   Partials: fp32, unnormalized, stored with the R18-proven clean C-layout
//   pattern (no fp16 sub-sector writes). (m,l) per row; merge in pooling.
// ---------------------------------------------------------------------------
#define QTILE 128
#define KTILE 64
#define KS_PITCH 136
#define KT_PITCH 72
#define PS_PITCH 72

__global__ __launch_bounds__(256, 4) void attn_mfma(const bf16_t* __restrict__ h2bf,
                                                    const bf16_t* __restrict__ h2T,
                                                    float* __restrict__ Op0,
                                                    float* __restrict__ Op1,
                                                    float* __restrict__ ml) {
    __shared__ __align__(16) bf16_t smem[18432];  // 36864 B

    int tid = threadIdx.x;
    int wv = tid >> 6, lane = tid & 63;
    int l15 = lane & 15, quad = lane >> 4;
    // swizzle: idx = xcd | half<<3 | qt<<4 | bhi<<7 ; b = bhi*8 + xcd
    int idx = blockIdx.x;
    int xcd = idx & 7;
    int half = (idx >> 3) & 1;
    int qt = (idx >> 4) & 7;
    int b = (idx >> 7) * 8 + xcd;
    const bf16_t* hb = h2bf + (size_t)b * NPG * DH;
    const bf16_t* hbT = h2T + (size_t)b * DH * NPG;

    bf16x8 bQ[2][4];
#pragma unroll
    for (int s = 0; s < 2; s++) {
        int qrow = qt * QTILE + wv * 32 + s * 16 + l15;
        int qsrc = (qrow < NPG) ? qrow : 0;
#pragma unroll
        for (int kb = 0; kb < 4; kb++)
            bQ[s][kb] = *(const bf16x8*)(hb + (size_t)qsrc * DH + kb * 32 + quad * 8);
    }

    float m_i[2] = {-1e30f, -1e30f}, l_i[2] = {0.f, 0.f};
    f32x4 O[2][8];
#pragma unroll
    for (int s = 0; s < 2; s++)
#pragma unroll
        for (int t = 0; t < 8; t++) O[s][t] = (f32x4){0.f, 0.f, 0.f, 0.f};

    for (int kt = half * 8; kt < half * 8 + 8; kt++) {
        __syncthreads();  // A: prev-iter PV reads of smem done
        for (int c = tid; c < KTILE * 16; c += 256) {
            int row = c >> 4, seg = c & 15;
            int key = kt * KTILE + row;
            uint4 v = {0u, 0u, 0u, 0u};
            if (key < NPG) v = *(const uint4*)(hb + (size_t)key * DH + seg * 8);
            *(uint4*)&smem[row * KS_PITCH + seg * 8] = v;
        }
        for (int c = tid; c < DH * 8; c += 256) {
            int dim = c >> 3, kc = c & 7;
            int key0 = kt * KTILE + kc * 8;
            uint4 v = {0u, 0u, 0u, 0u};
            if (key0 < NPG) v = *(const uint4*)(hbT + (size_t)dim * NPG + key0);
            *(uint4*)&smem[9216 + dim * KT_PITCH + kc * 8] = v;
        }
        __syncthreads();  // B: staging visible

        // ---- S^T = K Q^T (smem as Ks) ----
        f32x4 S[2][4];
#pragma unroll
        for (int nt = 0; nt < 4; nt++) {
            f32x4 acc0 = {0.f, 0.f, 0.f, 0.f};
            f32x4 acc1 = {0.f, 0.f, 0.f, 0.f};
#pragma unroll
            for (int kb = 0; kb < 4; kb++) {
                bf16x8 aK = *(const bf16x8*)&smem[(nt * 16 + l15) * KS_PITCH + kb * 32 + quad * 8];
                acc0 = __builtin_amdgcn_mfma_f32_16x16x32_bf16(aK, bQ[0][kb], acc0, 0, 0, 0);
                acc1 = __builtin_amdgcn_mfma_f32_16x16x32_bf16(aK, bQ[1][kb], acc1, 0, 0, 0);
            }
            S[0][nt] = acc0;
            S[1][nt] = acc1;
        }
        __syncthreads();  // C: Ks reads done before Ps overwrites smem

        float alpha[2];
#pragma unroll
        for (int s = 0; s < 2; s++) {
            float sm[4][4];
            float pmax = -1e30f;
#pragma unroll
            for (int nt = 0; nt < 4; nt++) {
                bool valid = (kt * KTILE + nt * 16) < NPG;  // 1008 = 63*16
#pragma unroll
                for (int r = 0; r < 4; r++) {
                    float v2 = valid ? S[s][nt][r] * ATT_SCALE : -1e30f;
                    sm[nt][r] = v2;
                    pmax = fmaxf(pmax, v2);
                }
            }
            pmax = fmaxf(pmax, __shfl_xor(pmax, 16));
            pmax = fmaxf(pmax, __shfl_xor(pmax, 32));
            float newm = fmaxf(m_i[s], pmax);
            alpha[s] = __expf(m_i[s] - newm);
            m_i[s] = newm;

            float psum = 0.f;
#pragma unroll
            for (int nt = 0; nt < 4; nt++) {
                bf16x4 pk;
#pragma unroll
                for (int r = 0; r < 4; r++) {
                    float p = __expf(sm[nt][r] - newm);
                    psum += p;
                    pk[r] = (bf16_t)p;
                }
                *(bf16x4*)&smem[(wv * 32 + s * 16 + l15) * PS_PITCH + nt * 16 + quad * 4] = pk;
            }
            psum += __shfl_xor(psum, 16);
            psum += __shfl_xor(psum, 32);
            l_i[s] = l_i[s] * alpha[s] + psum;

            float a0 = __shfl(alpha[s], quad * 4 + 0);
            float a1 = __shfl(alpha[s], quad * 4 + 1);
            float a2 = __shfl(alpha[s], quad * 4 + 2);
            float a3 = __shfl(alpha[s], quad * 4 + 3);
#pragma unroll
            for (int t = 0; t < 8; t++) {
                O[s][t][0] *= a0; O[s][t][1] *= a1;
                O[s][t][2] *= a2; O[s][t][3] *= a3;
            }
        }

        // ---- O += P V (smem as Ps — own-wave rows only) ----
#pragma unroll
        for (int kb2 = 0; kb2 < 2; kb2++) {
            bf16x8 aP0 = *(const bf16x8*)&smem[(wv * 32 + l15) * PS_PITCH + kb2 * 32 + quad * 8];
            bf16x8 aP1 = *(const bf16x8*)&smem[(wv * 32 + 16 + l15) * PS_PITCH + kb2 * 32 + quad * 8];
#pragma unroll
            for (int t = 0; t < 8; t++) {
                bf16x8 bV = *(const bf16x8*)&smem[9216 + (t * 16 + l15) * KT_PITCH + kb2 * 32 + quad * 8];
                O[0][t] = __builtin_amdgcn_mfma_f32_16x16x32_bf16(aP0, bV, O[0][t], 0, 0, 0);
                O[1][t] = __builtin_amdgcn_mfma_f32_16x16x32_bf16(aP1, bV, O[1][t], 0, 0, 0);
            }
        }
    }

    // ---- epilogue: fp32 UNNORMALIZED partials, R18-proven store pattern ----
    float* Op = half ? Op1 : Op0;
    float* mlh = ml + (size_t)half * N_NODES * 2;
    float* cb = Op + (size_t)b * NPG * DH;
#pragma unroll
    for (int s = 0; s < 2; s++) {
#pragma unroll
        for (int t = 0; t < 8; t++)
#pragma unroll
            for (int r = 0; r < 4; r++) {
                int qrow = qt * QTILE + wv * 32 + s * 16 + quad * 4 + r;
                if (qrow < NPG) cb[(size_t)qrow * DH + t * 16 + l15] = O[s][t][r];
            }
        if (quad == 0) {
            int qrow = qt * QTILE + wv * 32 + s * 16 + l15;
            if (qrow < NPG) {
                mlh[((size_t)b * NPG + qrow) * 2 + 0] = m_i[s];
                mlh[((size_t)b * NPG + qrow) * 2 + 1] = l_i[s];
            }
        }
    }
}

// ---------------------------------------------------------------------------
// pooling: merge the two attention partials on the fly + segmented max/mean
// -> feat[B,12,512]; blocks 0..255 also init y1raw with bias
// ---------------------------------------------------------------------------
__global__ __launch_bounds__(128) void pooling(const float* __restrict__ h1,
                                               const float* __restrict__ Op0,
                                               const float* __restrict__ Op1,
                                               const float* __restrict__ ml,
                                               const float* __restrict__ bf1,
                                               float* __restrict__ feat,
                                               float* __restrict__ y1raw) {
    int bs = blockIdx.x;
    int d = threadIdx.x;
    if (bs < 256) {
        int i = bs * 128 + d;
        y1raw[i] = bf1[i & 511];
    }
    int base = bs * NSEG;
    float mx1 = -1e30f, sm1 = 0.f, mx2 = -1e30f, sm2 = 0.f;
    for (int n = 0; n < NSEG; n++) {
        int ng = base + n;
        float v1 = h1[(size_t)ng * DH + d];
        mx1 = fmaxf(mx1, v1);
        sm1 += v1;
        float m1 = ml[(size_t)ng * 2 + 0];
        float l1 = ml[(size_t)ng * 2 + 1];
        float m2 = ml[((size_t)N_NODES + ng) * 2 + 0];
        float l2 = ml[((size_t)N_NODES + ng) * 2 + 1];
        float mm = fmaxf(m1, m2);
        float e1 = __expf(m1 - mm), e2 = __expf(m2 - mm);
        float inv = 1.0f / (l1 * e1 + l2 * e2);
        float o1 = Op0[(size_t)ng * DH + d];
        float o2 = Op1[(size_t)ng * DH + d];
        float v2 = (o1 * e1 + o2 * e2) * inv;
        mx2 = fmaxf(mx2, v2);
        sm2 += v2;
    }
    const float invs = 1.0f / NSEG;
    feat[bs * 512 + d] = mx1;
    feat[bs * 512 + 128 + d] = sm1 * invs;
    feat[bs * 512 + 256 + d] = mx2;
    feat[bs * 512 + 384 + d] = sm2 * invs;
}

// ---------------------------------------------------------------------------
// mlp1: split-K GEMM, fp32 atomic accumulation into bias-initialized y1raw
// ---------------------------------------------------------------------------
#define MLP1_KCH 96
__global__ __launch_bounds__(256) void mlp1_splitk(const float* __restrict__ feat,
                                                   const float* __restrict__ wf1,
                                                   float* __restrict__ y1raw) {
    __shared__ float fl[64][MLP1_KCH];
    int k0 = blockIdx.y * MLP1_KCH;
    int tid = threadIdx.x;
    for (int c = tid; c < 64 * MLP1_KCH; c += 256) {
        int row = c / MLP1_KCH;
        int kk = c - row * MLP1_KCH;
        fl[row][kk] = feat[(size_t)row * 6144 + k0 + kk];
    }
    __syncthreads();
    int col = blockIdx.x * 128 + (tid & 127);
    int rbase = (tid >> 7) * 32;
    float acc[32];
#pragma unroll
    for (int r = 0; r < 32; r++) acc[r] = 0.f;
    for (int kg = 0; kg < MLP1_KCH; kg += 4) {
        float w0 = wf1[(size_t)(k0 + kg + 0) * 512 + col];
        float w1 = wf1[(size_t)(k0 + kg + 1) * 512 + col];
        float w2 = wf1[(size_t)(k0 + kg + 2) * 512 + col];
        float w3 = wf1[(size_t)(k0 + kg + 3) * 512 + col];
#pragma unroll
        for (int r = 0; r < 32; r++) {
            float4 f = *(const float4*)&fl[rbase + r][kg];
            acc[r] += f.x * w0 + f.y * w1 + f.z * w2 + f.w * w3;
        }
    }
#pragma unroll
    for (int r = 0; r < 32; r++)
        atomicAdd(&y1raw[(size_t)(rbase + r) * 512 + col], acc[r]);
}

// ---------------------------------------------------------------------------
// head_tail: BN1(silu) -> mlp2 -> BN2 -> mlp3 -> softmax, one block.
// ---------------------------------------------------------------------------
__global__ __launch_bounds__(1024) void head_tail(const float* __restrict__ y1raw,
                                                  const float* __restrict__ g1,
                                                  const float* __restrict__ be1,
                                                  const float* __restrict__ wf2,
                                                  const float* __restrict__ bf2,
                                                  const float* __restrict__ g2,
                                                  const float* __restrict__ be2,
                                                  const float* __restrict__ wf3,
                                                  const float* __restrict__ bf3,
                                                  float* __restrict__ out) {
    __shared__ float sscale[512];
    __shared__ float sshift[512];
    __shared__ float zsm[64][68];
    __shared__ float y2sm[64][33];
    __shared__ float scale2[32], shift2[32];

    int tid = threadIdx.x;

    if (tid < 512) {
        float s = 0.f, s2 = 0.f;
        for (int b = 0; b < 64; b++) {
            float v = y1raw[b * 512 + tid];
            float h = v / (1.0f + __expf(-v));
            s += h;
            s2 += h * h;
        }
        float mu = s * (1.0f / 64.0f);
        float var = s2 * (1.0f / 64.0f) - mu * mu;
        float sc = rsqrtf(var + 1e-5f) * g1[tid];
        sscale[tid] = sc;
        sshift[tid] = be1[tid] - mu * sc;
    }
    __syncthreads();

    int b0 = tid >> 5;
    int b1 = b0 + 32;
    int j2 = tid & 31;
    float acc0 = bf2[j2], acc1 = acc0;
    for (int kc = 0; kc < 8; kc++) {
        __syncthreads();
#pragma unroll
        for (int c = 0; c < 4; c++) {
            int lin = tid + c * 1024;
            int bb = lin >> 6;
            int kk = lin & 63;
            int k = kc * 64 + kk;
            float v = y1raw[bb * 512 + k];
            float h = v / (1.0f + __expf(-v));
            zsm[bb][kk] = h * sscale[k] + sshift[k];
        }
        __syncthreads();
        for (int kk = 0; kk < 64; kk++) {
            float wv = wf2[(kc * 64 + kk) * 32 + j2];
            acc0 += zsm[b0][kk] * wv;
            acc1 += zsm[b1][kk] * wv;
        }
    }
    y2sm[b0][j2] = acc0;
    y2sm[b1][j2] = acc1;
    __syncthreads();

    if (tid < 32) {
        float s = 0.f, s2 = 0.f;
        for (int b = 0; b < 64; b++) {
            float h = y2sm[b][tid];
            float hs = h / (1.0f + __expf(-h));
            s += hs;
            s2 += hs * hs;
        }
        float mu = s * (1.0f / 64.0f);
        float var = s2 * (1.0f / 64.0f) - mu * mu;
        float sc = rsqrtf(var + 1e-5f) * g2[tid];
        scale2[tid] = sc;
        shift2[tid] = be2[tid] - mu * sc;
    }
    __syncthreads();

    if (tid < 64) {
        float l0 = bf3[0], l1 = bf3[1];
        for (int k = 0; k < 32; k++) {
            float h = y2sm[tid][k];
            float hs = h / (1.0f + __expf(-h));
            float v = hs * scale2[k] + shift2[k];
            l0 += v * wf3[k * 2 + 0];
            l1 += v * wf3[k * 2 + 1];
        }
        float m = fmaxf(l0, l1);
        float e0 = __expf(l0 - m), e1 = __expf(l1 - m);
        float inv = 1.0f / (e0 + e1);
        out[tid * 2 + 0] = e0 * inv;
        out[tid * 2 + 1] = e1 * inv;
    }
}

// ---------------------------------------------------------------------------
extern "C" void kernel_launch(void* const* d_in, const int* in_sizes, int n_in,
                              void* d_out, int out_size, void* d_ws, size_t ws_size,
                              hipStream_t stream) {
    const float* x   = (const float*)d_in[0];
    const int*   ei  = (const int*)d_in[1];
    const float* w1  = (const float*)d_in[2];
    const float* b1  = (const float*)d_in[3];
    const float* w2  = (const float*)d_in[4];
    const float* b2  = (const float*)d_in[5];
    const float* pe  = (const float*)d_in[6];
    const float* wf1 = (const float*)d_in[7];
    const float* bf1 = (const float*)d_in[8];
    const float* g1  = (const float*)d_in[9];
    const float* be1 = (const float*)d_in[10];
    const float* wf2 = (const float*)d_in[11];
    const float* bf2 = (const float*)d_in[12];
    const float* g2  = (const float*)d_in[13];
    const float* be2 = (const float*)d_in[14];
    const float* wf3 = (const float*)d_in[15];
    const float* bf3 = (const float*)d_in[16];
    float* out = (float*)d_out;

    const int* srcp = ei;
    const int* dstp = ei + NEDGE;

    // workspace layout
    float* ws = (float*)d_ws;
    size_t off = 0;
    float* h1   = ws + off; off += (size_t)N_NODES * DH;
    float* Op0  = ws + off; off += (size_t)N_NODES * DH;
    float* Op1  = ws + off; off += (size_t)N_NODES * DH;
    float* ml   = ws + off; off += (size_t)2 * N_NODES * 2;
    float* feat = ws + off; off += (size_t)BG * NSNAP * 512;
    bf16_t* h2bf = (bf16_t*)(ws + off); off += (size_t)N_NODES * DH / 2;
    bf16_t* h2T  = (bf16_t*)(ws + off); off += (size_t)N_NODES * DH / 2;
    f16_t* h1h   = (f16_t*)(ws + off);  off += (size_t)N_NODES * DH / 2;
    f16_t* xh    = (f16_t*)(ws + off);  off += (size_t)(N_NODES * DIN + 2) / 2;
    float* y1raw = ws + off; off += 64 * 512;
    int* cnt  = (int*)(ws + off);
    int* eidx = cnt + N_NODES;

    cvt_xh<<<(N_NODES * DIN / 4 + 255) / 256, 256, 0, stream>>>(x, xh, cnt);
    fill_pad<<<(NEDGE + 255) / 256, 256, 0, stream>>>(srcp, dstp, cnt, eidx);

    gin1<<<N_NODES / 8, 128, 0, stream>>>(x, xh, cnt, eidx, w1, b1, h1, h1h);
    gin2<<<N_NODES / 8, 128, 0, stream>>>(h1, h1h, cnt, eidx, w2, b2, pe, h2bf, h2T);
    attn_mfma<<<BG * 16, 256, 0, stream>>>(h2bf, h2T, Op0, Op1, ml);
    pooling<<<BG * NSNAP, 128, 0, stream>>>(h1, Op0, Op1, ml, bf1, feat, y1raw);
    mlp1_splitk<<<dim3(4, 64), 256, 0, stream>>>(feat, wf1, y1raw);
    head_tail<<<1, 1024, 0, stream>>>(y1raw, g1, be1, wf2, bf2, g2, be2, wf3, bf3, out);
}

// Round 20
// 470.667 us; speedup vs baseline: 1.2108x; 1.2108x over previous
//
#include <hip/hip_runtime.h>
#include <math.h>

#define N_NODES 64512
#define DIN 84
#define DH 128
#define NPG 1008
#define BG 64
#define NSNAP 12
#define NSEG 84
#define NEDGE (N_NODES * 16)
#define DEGCAP 64
#define ATT_SCALE 0.08838834764831845f /* 1/sqrt(128) */

typedef __bf16 bf16_t;
typedef __bf16 bf16x8 __attribute__((ext_vector_type(8)));
typedef __bf16 bf16x4 __attribute__((ext_vector_type(4)));
typedef float f32x4 __attribute__((ext_vector_type(4)));
typedef _Float16 f16_t;
typedef _Float16 f16x4 __attribute__((ext_vector_type(4)));

__device__ __forceinline__ f32x4 up4(f16x4 v) {
    return (f32x4){(float)v[0], (float)v[1], (float)v[2], (float)v[3]};
}

// ---------------------------------------------------------------------------
// cvt_xh: x -> fp16 copy; low blocks also zero the CSR counters
// ---------------------------------------------------------------------------
__global__ __launch_bounds__(256) void cvt_xh(const float* __restrict__ x,
                                              f16_t* __restrict__ xh,
                                              int* __restrict__ cnt) {
    int t = blockIdx.x * 256 + threadIdx.x;
    int idx = t * 4;
    if (idx < N_NODES * DIN) {
        f32x4 v = *(const f32x4*)(x + idx);
        f16x4 o;
        o[0] = (f16_t)v[0]; o[1] = (f16_t)v[1];
        o[2] = (f16_t)v[2]; o[3] = (f16_t)v[3];
        *(f16x4*)(xh + idx) = o;
    }
    if (idx < N_NODES) {
        int4 z = {0, 0, 0, 0};
        *(int4*)(cnt + idx) = z;
    }
}

// ---------------------------------------------------------------------------
// Padded-CSR build: one atomic pass. deg ~ Poisson(16), P(deg>64) ~ 0.
// ---------------------------------------------------------------------------
__global__ void fill_pad(const int* __restrict__ src, const int* __restrict__ dst,
                         int* __restrict__ cnt, int* __restrict__ eidx) {
    int e = blockIdx.x * blockDim.x + threadIdx.x;
    if (e < NEDGE) {
        int d = dst[e];
        int p = atomicAdd(&cnt[d], 1);
        if (p < DEGCAP) eidx[(size_t)d * DEGCAP + p] = src[e];
    }
}

// ---------------------------------------------------------------------------
// gin1: fused gather(fp16 x) + linear1
// ---------------------------------------------------------------------------
__global__ __launch_bounds__(128) void gin1(const float* __restrict__ x,
                                            const f16_t* __restrict__ xh,
                                            const int* __restrict__ cnt,
                                            const int* __restrict__ eidx,
                                            const float* __restrict__ w1,
                                            const float* __restrict__ b1,
                                            float* __restrict__ h1,
                                            f16_t* __restrict__ h1h) {
    __shared__ float xs[8][DIN];
    int n0 = blockIdx.x * 8;
    int tid = threadIdx.x;
    int grp = tid >> 4;
    int gl = tid & 15;
    int node = n0 + grp;
    int s = node * DEGCAP;
    int e = s + min(cnt[node], DEGCAP);
    bool has2 = gl < 5;

    const float* xn = x + (size_t)node * DIN;
    f32x4 a0 = *(const f32x4*)(xn + gl * 4);
    f32x4 a1 = has2 ? *(const f32x4*)(xn + 64 + gl * 4) : (f32x4){0.f, 0.f, 0.f, 0.f};

    int i = s;
    for (; i + 4 <= e; i += 4) {
        const f16_t* p0 = xh + (size_t)eidx[i] * DIN + gl * 4;
        const f16_t* p1 = xh + (size_t)eidx[i + 1] * DIN + gl * 4;
        const f16_t* p2 = xh + (size_t)eidx[i + 2] * DIN + gl * 4;
        const f16_t* p3 = xh + (size_t)eidx[i + 3] * DIN + gl * 4;
        a0 += up4(*(const f16x4*)p0) + up4(*(const f16x4*)p1) +
              up4(*(const f16x4*)p2) + up4(*(const f16x4*)p3);
        if (has2) {
            a1 += up4(*(const f16x4*)(p0 + 64)) + up4(*(const f16x4*)(p1 + 64)) +
                  up4(*(const f16x4*)(p2 + 64)) + up4(*(const f16x4*)(p3 + 64));
        }
    }
    for (; i < e; i++) {
        const f16_t* p0 = xh + (size_t)eidx[i] * DIN + gl * 4;
        a0 += up4(*(const f16x4*)p0);
        if (has2) a1 += up4(*(const f16x4*)(p0 + 64));
    }
    *(f32x4*)&xs[grp][gl * 4] = a0;
    if (has2) *(f32x4*)&xs[grp][64 + gl * 4] = a1;
    __syncthreads();

    float acc[8];
    float bias = b1[tid];
#pragma unroll
    for (int r = 0; r < 8; r++) acc[r] = bias;
    for (int k = 0; k < DIN; k++) {
        float w = w1[k * DH + tid];
#pragma unroll
        for (int r = 0; r < 8; r++) acc[r] += xs[r][k] * w;
    }
#pragma unroll
    for (int r = 0; r < 8; r++) {
        h1[(size_t)(n0 + r) * DH + tid] = acc[r];
        h1h[(size_t)(n0 + r) * DH + tid] = (f16_t)acc[r];
    }
}

// ---------------------------------------------------------------------------
// gin2: fused gather(fp16 h1) + linear2 + pe; emits h2bf AND h2T directly.
// ---------------------------------------------------------------------------
__global__ __launch_bounds__(128) void gin2(const float* __restrict__ h1,
                                            const f16_t* __restrict__ h1h,
                                            const int* __restrict__ cnt,
                                            const int* __restrict__ eidx,
                                            const float* __restrict__ w2,
                                            const float* __restrict__ b2,
                                            const float* __restrict__ pe,
                                            bf16_t* __restrict__ h2bf,
                                            bf16_t* __restrict__ h2T) {
    __shared__ float hs[8][DH];
    int n0 = blockIdx.x * 8;
    int tid = threadIdx.x;
    int grp = tid >> 4;
    int gl = tid & 15;
    int node = n0 + grp;
    int s = node * DEGCAP;
    int e = s + min(cnt[node], DEGCAP);

    const float* hn = h1 + (size_t)node * DH;
    f32x4 a0 = *(const f32x4*)(hn + gl * 8);
    f32x4 a1 = *(const f32x4*)(hn + gl * 8 + 4);

    int i = s;
    for (; i + 4 <= e; i += 4) {
        const f16_t* p0 = h1h + (size_t)eidx[i] * DH + gl * 8;
        const f16_t* p1 = h1h + (size_t)eidx[i + 1] * DH + gl * 8;
        const f16_t* p2 = h1h + (size_t)eidx[i + 2] * DH + gl * 8;
        const f16_t* p3 = h1h + (size_t)eidx[i + 3] * DH + gl * 8;
        a0 += up4(*(const f16x4*)p0) + up4(*(const f16x4*)p1) +
              up4(*(const f16x4*)p2) + up4(*(const f16x4*)p3);
        a1 += up4(*(const f16x4*)(p0 + 4)) + up4(*(const f16x4*)(p1 + 4)) +
              up4(*(const f16x4*)(p2 + 4)) + up4(*(const f16x4*)(p3 + 4));
    }
    for (; i < e; i++) {
        const f16_t* p0 = h1h + (size_t)eidx[i] * DH + gl * 8;
        a0 += up4(*(const f16x4*)p0);
        a1 += up4(*(const f16x4*)(p0 + 4));
    }
    *(f32x4*)&hs[grp][gl * 8] = a0;
    *(f32x4*)&hs[grp][gl * 8 + 4] = a1;
    __syncthreads();

    float acc[8];
    float bias = b2[tid];
#pragma unroll
    for (int r = 0; r < 8; r++) acc[r] = bias;
    for (int k = 0; k < DH; k++) {
        float w = w2[k * DH + tid];
#pragma unroll
        for (int r = 0; r < 8; r++) acc[r] += hs[r][k] * w;
    }

    int bg = n0 / NPG;
    int pos0 = n0 - bg * NPG;
    bf16x8 tv;
#pragma unroll
    for (int r = 0; r < 8; r++) {
        bf16_t v = (bf16_t)(acc[r] + pe[(pos0 + r) * DH + tid]);
        h2bf[(size_t)(n0 + r) * DH + tid] = v;
        tv[r] = v;
    }
    *(bf16x8*)(h2T + ((size_t)bg * DH + tid) * NPG + pos0) = tv;
}

// ---------------------------------------------------------------------------
// Flash MFMA attention: QTILE=64 (16 q-rows/wave, one Q-set), grid 1024,
// XCD swizzle (proven R18), Ks/Ps LDS union -> 35840 B -> 4 blocks/CU
// (16 waves/CU, 2x the latency-hiding of R18). No split-K, no partials.
// Barriers per tile: A (prev PV reads done) - stage - B - S - C (Ks reads
// done before Ps overwrite) - softmax/Ps(wave-private)/PV.
// ---------------------------------------------------------------------------
#define QTILE 64
#define KTILE 64
#define KS_PITCH 136
#define KT_PITCH 72
#define PS_PITCH 72
#define KT_OFF 8704  /* bf16 elems; Ks union = 64*136 = 8704 */

__global__ __launch_bounds__(256, 4) void attn_mfma(const bf16_t* __restrict__ h2bf,
                                                    const bf16_t* __restrict__ h2T,
                                                    float* __restrict__ ctx) {
    __shared__ __align__(16) bf16_t smem[KT_OFF + DH * KT_PITCH];  // 35840 B

    int tid = threadIdx.x;
    int wv = tid >> 6, lane = tid & 63;
    int l15 = lane & 15, quad = lane >> 4;
    // swizzle: idx = xcd | qt<<3 | bhi<<7 ; b = bhi*8 + xcd (grid 1024)
    int idx = blockIdx.x;
    int xcd = idx & 7;
    int qt = (idx >> 3) & 15;
    int b = (idx >> 7) * 8 + xcd;
    const bf16_t* hb = h2bf + (size_t)b * NPG * DH;
    const bf16_t* hbT = h2T + (size_t)b * DH * NPG;

    // ---- Q B-fragments: wave wv owns q-rows qt*64 + wv*16 + l15 ----
    int qrow_frag = qt * QTILE + wv * 16 + l15;
    int qsrc = (qrow_frag < NPG) ? qrow_frag : 0;
    bf16x8 bQ[4];
#pragma unroll
    for (int kb = 0; kb < 4; kb++)
        bQ[kb] = *(const bf16x8*)(hb + (size_t)qsrc * DH + kb * 32 + quad * 8);

    float m_i = -1e30f, l_i = 0.0f;
    f32x4 O[8];
#pragma unroll
    for (int t = 0; t < 8; t++) O[t] = (f32x4){0.f, 0.f, 0.f, 0.f};

    for (int kt = 0; kt < 16; kt++) {
        __syncthreads();  // A: prev-iter PV reads of smem done
        for (int c = tid; c < KTILE * 16; c += 256) {
            int row = c >> 4, seg = c & 15;
            int key = kt * KTILE + row;
            uint4 v = {0u, 0u, 0u, 0u};
            if (key < NPG) v = *(const uint4*)(hb + (size_t)key * DH + seg * 8);
            *(uint4*)&smem[row * KS_PITCH + seg * 8] = v;
        }
        for (int c = tid; c < DH * 8; c += 256) {
            int dim = c >> 3, kc = c & 7;
            int key0 = kt * KTILE + kc * 8;
            uint4 v = {0u, 0u, 0u, 0u};
            if (key0 < NPG) v = *(const uint4*)(hbT + (size_t)dim * NPG + key0);
            *(uint4*)&smem[KT_OFF + dim * KT_PITCH + kc * 8] = v;
        }
        __syncthreads();  // B: staging visible

        // ---- S^T = K Q^T (smem as Ks) ----
        f32x4 S[4];
#pragma unroll
        for (int nt = 0; nt < 4; nt++) {
            f32x4 acc = {0.f, 0.f, 0.f, 0.f};
#pragma unroll
            for (int kb = 0; kb < 4; kb++) {
                bf16x8 aK = *(const bf16x8*)&smem[(nt * 16 + l15) * KS_PITCH + kb * 32 + quad * 8];
                acc = __builtin_amdgcn_mfma_f32_16x16x32_bf16(aK, bQ[kb], acc, 0, 0, 0);
            }
            S[nt] = acc;
        }
        __syncthreads();  // C: Ks reads done before Ps overwrites smem

        // ---- scale + mask + online softmax ----
        float sm[4][4];
        float pmax = -1e30f;
#pragma unroll
        for (int nt = 0; nt < 4; nt++) {
            bool valid = (kt * KTILE + nt * 16) < NPG;  // 1008 = 63*16
#pragma unroll
            for (int r = 0; r < 4; r++) {
                float v2 = valid ? S[nt][r] * ATT_SCALE : -1e30f;
                sm[nt][r] = v2;
                pmax = fmaxf(pmax, v2);
            }
        }
        pmax = fmaxf(pmax, __shfl_xor(pmax, 16));
        pmax = fmaxf(pmax, __shfl_xor(pmax, 32));
        float newm = fmaxf(m_i, pmax);
        float alpha = __expf(m_i - newm);
        m_i = newm;

        float psum = 0.f;
#pragma unroll
        for (int nt = 0; nt < 4; nt++) {
            bf16x4 pk;
#pragma unroll
            for (int r = 0; r < 4; r++) {
                float p = __expf(sm[nt][r] - newm);
                psum += p;
                pk[r] = (bf16_t)p;
            }
            *(bf16x4*)&smem[(wv * 16 + l15) * PS_PITCH + nt * 16 + quad * 4] = pk;
        }
        psum += __shfl_xor(psum, 16);
        psum += __shfl_xor(psum, 32);
        l_i = l_i * alpha + psum;

        float a0 = __shfl(alpha, quad * 4 + 0);
        float a1 = __shfl(alpha, quad * 4 + 1);
        float a2 = __shfl(alpha, quad * 4 + 2);
        float a3 = __shfl(alpha, quad * 4 + 3);
#pragma unroll
        for (int t = 0; t < 8; t++) {
            O[t][0] *= a0; O[t][1] *= a1; O[t][2] *= a2; O[t][3] *= a3;
        }

        // ---- O += P V (smem as Ps — own-wave rows; Kt region) ----
#pragma unroll
        for (int kb2 = 0; kb2 < 2; kb2++) {
            bf16x8 aP = *(const bf16x8*)&smem[(wv * 16 + l15) * PS_PITCH + kb2 * 32 + quad * 8];
#pragma unroll
            for (int t = 0; t < 8; t++) {
                bf16x8 bV = *(const bf16x8*)&smem[KT_OFF + (t * 16 + l15) * KT_PITCH + kb2 * 32 + quad * 8];
                O[t] = __builtin_amdgcn_mfma_f32_16x16x32_bf16(aP, bV, O[t], 0, 0, 0);
            }
        }
    }

    // ---- epilogue ----
    float invl[4];
#pragma unroll
    for (int r = 0; r < 4; r++) invl[r] = 1.0f / __shfl(l_i, quad * 4 + r);
    float* cb = ctx + (size_t)b * NPG * DH;
#pragma unroll
    for (int t = 0; t < 8; t++)
#pragma unroll
        for (int r = 0; r < 4; r++) {
            int qrow = qt * QTILE + wv * 16 + quad * 4 + r;
            if (qrow < NPG) cb[(size_t)qrow * DH + t * 16 + l15] = O[t][r] * invl[r];
        }
}

// ---------------------------------------------------------------------------
// pooling: segmented max/mean -> feat[B,12,512]; blocks 0..255 init y1raw
// ---------------------------------------------------------------------------
__global__ __launch_bounds__(128) void pooling(const float* __restrict__ h1,
                                               const float* __restrict__ ctx,
                                               const float* __restrict__ bf1,
                                               float* __restrict__ feat,
                                               float* __restrict__ y1raw) {
    int bs = blockIdx.x;
    int d = threadIdx.x;
    if (bs < 256) {
        int i = bs * 128 + d;
        y1raw[i] = bf1[i & 511];
    }
    int base = bs * NSEG;
    float mx1 = -1e30f, sm1 = 0.f, mx2 = -1e30f, sm2 = 0.f;
    for (int n = 0; n < NSEG; n++) {
        float v1 = h1[(size_t)(base + n) * DH + d];
        mx1 = fmaxf(mx1, v1);
        sm1 += v1;
        float v2 = ctx[(size_t)(base + n) * DH + d];
        mx2 = fmaxf(mx2, v2);
        sm2 += v2;
    }
    const float invs = 1.0f / NSEG;
    feat[bs * 512 + d] = mx1;
    feat[bs * 512 + 128 + d] = sm1 * invs;
    feat[bs * 512 + 256 + d] = mx2;
    feat[bs * 512 + 384 + d] = sm2 * invs;
}

// ---------------------------------------------------------------------------
// mlp1: split-K GEMM, fp32 atomic accumulation into bias-initialized y1raw
// ---------------------------------------------------------------------------
#define MLP1_KCH 96
__global__ __launch_bounds__(256) void mlp1_splitk(const float* __restrict__ feat,
                                                   const float* __restrict__ wf1,
                                                   float* __restrict__ y1raw) {
    __shared__ float fl[64][MLP1_KCH];
    int k0 = blockIdx.y * MLP1_KCH;
    int tid = threadIdx.x;
    for (int c = tid; c < 64 * MLP1_KCH; c += 256) {
        int row = c / MLP1_KCH;
        int kk = c - row * MLP1_KCH;
        fl[row][kk] = feat[(size_t)row * 6144 + k0 + kk];
    }
    __syncthreads();
    int col = blockIdx.x * 128 + (tid & 127);
    int rbase = (tid >> 7) * 32;
    float acc[32];
#pragma unroll
    for (int r = 0; r < 32; r++) acc[r] = 0.f;
    for (int kg = 0; kg < MLP1_KCH; kg += 4) {
        float w0 = wf1[(size_t)(k0 + kg + 0) * 512 + col];
        float w1 = wf1[(size_t)(k0 + kg + 1) * 512 + col];
        float w2 = wf1[(size_t)(k0 + kg + 2) * 512 + col];
        float w3 = wf1[(size_t)(k0 + kg + 3) * 512 + col];
#pragma unroll
        for (int r = 0; r < 32; r++) {
            float4 f = *(const float4*)&fl[rbase + r][kg];
            acc[r] += f.x * w0 + f.y * w1 + f.z * w2 + f.w * w3;
        }
    }
#pragma unroll
    for (int r = 0; r < 32; r++)
        atomicAdd(&y1raw[(size_t)(rbase + r) * 512 + col], acc[r]);
}

// ---------------------------------------------------------------------------
// head_tail: BN1(silu) -> mlp2 -> BN2 -> mlp3 -> softmax, one block.
// ---------------------------------------------------------------------------
__global__ __launch_bounds__(1024) void head_tail(const float* __restrict__ y1raw,
                                                  const float* __restrict__ g1,
                                                  const float* __restrict__ be1,
                                                  const float* __restrict__ wf2,
                                                  const float* __restrict__ bf2,
                                                  const float* __restrict__ g2,
                                                  const float* __restrict__ be2,
                                                  const float* __restrict__ wf3,
                                                  const float* __restrict__ bf3,
                                                  float* __restrict__ out) {
    __shared__ float sscale[512];
    __shared__ float sshift[512];
    __shared__ float zsm[64][68];
    __shared__ float y2sm[64][33];
    __shared__ float scale2[32], shift2[32];

    int tid = threadIdx.x;

    if (tid < 512) {
        float s = 0.f, s2 = 0.f;
        for (int b = 0; b < 64; b++) {
            float v = y1raw[b * 512 + tid];
            float h = v / (1.0f + __expf(-v));
            s += h;
            s2 += h * h;
        }
        float mu = s * (1.0f / 64.0f);
        float var = s2 * (1.0f / 64.0f) - mu * mu;
        float sc = rsqrtf(var + 1e-5f) * g1[tid];
        sscale[tid] = sc;
        sshift[tid] = be1[tid] - mu * sc;
    }
    __syncthreads();

    int b0 = tid >> 5;
    int b1 = b0 + 32;
    int j2 = tid & 31;
    float acc0 = bf2[j2], acc1 = acc0;
    for (int kc = 0; kc < 8; kc++) {
        __syncthreads();
#pragma unroll
        for (int c = 0; c < 4; c++) {
            int lin = tid + c * 1024;
            int bb = lin >> 6;
            int kk = lin & 63;
            int k = kc * 64 + kk;
            float v = y1raw[bb * 512 + k];
            float h = v / (1.0f + __expf(-v));
            zsm[bb][kk] = h * sscale[k] + sshift[k];
        }
        __syncthreads();
        for (int kk = 0; kk < 64; kk++) {
            float wv = wf2[(kc * 64 + kk) * 32 + j2];
            acc0 += zsm[b0][kk] * wv;
            acc1 += zsm[b1][kk] * wv;
        }
    }
    y2sm[b0][j2] = acc0;
    y2sm[b1][j2] = acc1;
    __syncthreads();

    if (tid < 32) {
        float s = 0.f, s2 = 0.f;
        for (int b = 0; b < 64; b++) {
            float h = y2sm[b][tid];
            float hs = h / (1.0f + __expf(-h));
            s += hs;
            s2 += hs * hs;
        }
        float mu = s * (1.0f / 64.0f);
        float var = s2 * (1.0f / 64.0f) - mu * mu;
        float sc = rsqrtf(var + 1e-5f) * g2[tid];
        scale2[tid] = sc;
        shift2[tid] = be2[tid] - mu * sc;
    }
    __syncthreads();

    if (tid < 64) {
        float l0 = bf3[0], l1 = bf3[1];
        for (int k = 0; k < 32; k++) {
            float h = y2sm[tid][k];
            float hs = h / (1.0f + __expf(-h));
            float v = hs * scale2[k] + shift2[k];
            l0 += v * wf3[k * 2 + 0];
            l1 += v * wf3[k * 2 + 1];
        }
        float m = fmaxf(l0, l1);
        float e0 = __expf(l0 - m), e1 = __expf(l1 - m);
        float inv = 1.0f / (e0 + e1);
        out[tid * 2 + 0] = e0 * inv;
        out[tid * 2 + 1] = e1 * inv;
    }
}

// ---------------------------------------------------------------------------
extern "C" void kernel_launch(void* const* d_in, const int* in_sizes, int n_in,
                              void* d_out, int out_size, void* d_ws, size_t ws_size,
                              hipStream_t stream) {
    const float* x   = (const float*)d_in[0];
    const int*   ei  = (const int*)d_in[1];
    const float* w1  = (const float*)d_in[2];
    const float* b1  = (const float*)d_in[3];
    const float* w2  = (const float*)d_in[4];
    const float* b2  = (const float*)d_in[5];
    const float* pe  = (const float*)d_in[6];
    const float* wf1 = (const float*)d_in[7];
    const float* bf1 = (const float*)d_in[8];
    const float* g1  = (const float*)d_in[9];
    const float* be1 = (const float*)d_in[10];
    const float* wf2 = (const float*)d_in[11];
    const float* bf2 = (const float*)d_in[12];
    const float* g2  = (const float*)d_in[13];
    const float* be2 = (const float*)d_in[14];
    const float* wf3 = (const float*)d_in[15];
    const float* bf3 = (const float*)d_in[16];
    float* out = (float*)d_out;

    const int* srcp = ei;
    const int* dstp = ei + NEDGE;

    // workspace layout (R18)
    float* ws = (float*)d_ws;
    size_t off = 0;
    float* h1   = ws + off; off += (size_t)N_NODES * DH;
    float* ctxb = ws + off; off += (size_t)N_NODES * DH;
    float* feat = ws + off; off += (size_t)BG * NSNAP * 512;
    bf16_t* h2bf = (bf16_t*)(ws + off); off += (size_t)N_NODES * DH / 2;
    bf16_t* h2T  = (bf16_t*)(ws + off); off += (size_t)N_NODES * DH / 2;
    f16_t* h1h   = (f16_t*)(ws + off);  off += (size_t)N_NODES * DH / 2;
    f16_t* xh    = (f16_t*)(ws + off);  off += (size_t)(N_NODES * DIN + 2) / 2;
    float* y1raw = ws + off; off += 64 * 512;
    int* cnt  = (int*)(ws + off);
    int* eidx = cnt + N_NODES;

    cvt_xh<<<(N_NODES * DIN / 4 + 255) / 256, 256, 0, stream>>>(x, xh, cnt);
    fill_pad<<<(NEDGE + 255) / 256, 256, 0, stream>>>(srcp, dstp, cnt, eidx);

    gin1<<<N_NODES / 8, 128, 0, stream>>>(x, xh, cnt, eidx, w1, b1, h1, h1h);
    gin2<<<N_NODES / 8, 128, 0, stream>>>(h1, h1h, cnt, eidx, w2, b2, pe, h2bf, h2T);
    attn_mfma<<<BG * 16, 256, 0, stream>>>(h2bf, h2T, ctxb);
    pooling<<<BG * NSNAP, 128, 0, stream>>>(h1, ctxb, bf1, feat, y1raw);
    mlp1_splitk<<<dim3(4, 64), 256, 0, stream>>>(feat, wf1, y1raw);
    head_tail<<<1, 1024, 0, stream>>>(y1raw, g1, be1, wf2, bf2, g2, be2, wf3, bf3, out);
}